// Round 1
// baseline (1019.529 us; speedup 1.0000x reference)
//
#include <hip/hip_runtime.h>
#include <stdint.h>

#define T_TOK 8192
#define DDIM 1024
#define EEXP 8
#define FDIM 2048

typedef float f32x4 __attribute__((ext_vector_type(4)));
typedef __bf16 bf16x8 __attribute__((ext_vector_type(8)));

__device__ __forceinline__ unsigned short f2bf(float f) {
  union { float f; unsigned int u; } v; v.f = f;
  unsigned int r = (v.u + 0x7fffu + ((v.u >> 16) & 1u)) >> 16;
  return (unsigned short)r;
}

__device__ __forceinline__ void async_cp16(const void* g, void* l) {
  __builtin_amdgcn_global_load_lds(
      (const __attribute__((address_space(1))) unsigned int*)g,
      (__attribute__((address_space(3))) unsigned int*)l, 16, 0, 0);
}

// ---------------- cast x fp32 -> bf16 ----------------
__global__ __launch_bounds__(256) void castx_kernel(const float* __restrict__ in,
                                                    unsigned short* __restrict__ out,
                                                    int n4) {
  int i = blockIdx.x * 256 + threadIdx.x;
  if (i >= n4) return;
  float4 v = ((const float4*)in)[i];
  ushort4 o;
  o.x = f2bf(v.x); o.y = f2bf(v.y); o.z = f2bf(v.z); o.w = f2bf(v.w);
  ((ushort4*)out)[i] = o;
}

// ---------------- transpose-cast weights: in [e][R][C] fp32 -> out [e][C][R] bf16 ----
__global__ void transpose_cast_kernel(const float* __restrict__ in,
                                      unsigned short* __restrict__ out,
                                      int R, int C) {
  __shared__ float tile[32][33];
  const size_t ebase = (size_t)blockIdx.z * R * C;
  int c0 = blockIdx.x * 32;
  int r0 = blockIdx.y * 32;
  int tx = threadIdx.x;
  int ty = threadIdx.y;
#pragma unroll
  for (int i = 0; i < 32; i += 8)
    tile[ty + i][tx] = in[ebase + (size_t)(r0 + ty + i) * C + c0 + tx];
  __syncthreads();
#pragma unroll
  for (int i = 0; i < 32; i += 8)
    out[ebase + (size_t)(c0 + ty + i) * R + r0 + tx] = f2bf(tile[tx][ty + i]);
}

// ---------------- gating: wave per token ----------------
// hdr layout (ints): [0..7]=cnt, [8..15]=fill, [16..24]=offs
__global__ __launch_bounds__(256) void gate_kernel(const float* __restrict__ x,
                                                   const float* __restrict__ wg,
                                                   int* __restrict__ sel,
                                                   float* __restrict__ prb,
                                                   int* __restrict__ hdr) {
  __shared__ float wgs[8 * 1024];  // transposed [e][d]
  int tid = threadIdx.x;
  for (int i = tid; i < 8192; i += 256) {
    int d = i >> 3, e = i & 7;
    wgs[e * 1024 + d] = wg[i];
  }
  __syncthreads();
  int lane = tid & 63;
  int t = blockIdx.x * 4 + (tid >> 6);
  const float* xr = x + (size_t)t * 1024;
  float acc[8] = {0.f, 0.f, 0.f, 0.f, 0.f, 0.f, 0.f, 0.f};
  for (int d = lane; d < 1024; d += 64) {
    float xv = xr[d];
#pragma unroll
    for (int e = 0; e < 8; e++) acc[e] += xv * wgs[e * 1024 + d];
  }
#pragma unroll
  for (int e = 0; e < 8; e++) {
    acc[e] += __shfl_xor(acc[e], 32);
    acc[e] += __shfl_xor(acc[e], 16);
    acc[e] += __shfl_xor(acc[e], 8);
    acc[e] += __shfl_xor(acc[e], 4);
    acc[e] += __shfl_xor(acc[e], 2);
    acc[e] += __shfl_xor(acc[e], 1);
  }
  if (lane == 0) {
    int i0 = 0; float v0 = acc[0];
#pragma unroll
    for (int e = 1; e < 8; e++) if (acc[e] > v0) { v0 = acc[e]; i0 = e; }
    int i1 = -1; float v1 = -1e30f;
#pragma unroll
    for (int e = 0; e < 8; e++) if (e != i0 && acc[e] > v1) { v1 = acc[e]; i1 = e; }
    float ex = __expf(v1 - v0);
    float inv = 1.0f / (1.0f + ex);
    sel[t * 2] = i0; sel[t * 2 + 1] = i1;
    prb[t * 2] = inv; prb[t * 2 + 1] = ex * inv;
    atomicAdd(&hdr[i0], 1);
    atomicAdd(&hdr[i1], 1);
  }
}

__global__ void scan_kernel(int* hdr) {
  if (threadIdx.x == 0 && blockIdx.x == 0) {
    int s = 0;
    for (int e = 0; e < 8; e++) { hdr[16 + e] = s; s += hdr[e]; }
    hdr[24] = s;
  }
}

__global__ __launch_bounds__(256) void build_kernel(const int* __restrict__ sel,
                                                    const float* __restrict__ prb,
                                                    int* __restrict__ hdr,
                                                    int* __restrict__ rows,
                                                    float* __restrict__ pslot) {
  int i = blockIdx.x * 256 + threadIdx.x;
  if (i >= T_TOK * 2) return;
  int e = sel[i];
  int pos = hdr[16 + e] + atomicAdd(&hdr[8 + e], 1);
  rows[pos] = i >> 1;
  pslot[pos] = prb[i];
}

// ---------------- GEMM1: h = silu(x@w1) * (x@w3), gathered rows, per expert ------
__global__ __launch_bounds__(256) void gemm1_kernel(
    const unsigned short* __restrict__ xb,   // [T][D] bf16
    const unsigned short* __restrict__ w1t,  // [E][F][D] bf16
    const unsigned short* __restrict__ w3t,  // [E][F][D] bf16
    const int* __restrict__ rows,            // slot -> token
    const int* __restrict__ hdr,
    unsigned short* __restrict__ h)          // [T*2][F] bf16 (slot space)
{
  const int e = blockIdx.z;
  const int count = hdr[e];
  const int m0 = blockIdx.y * 128;
  if (m0 >= count) return;
  const int n0 = blockIdx.x * 128;
  const int sbase = hdr[16 + e];

  __shared__ unsigned short As[128 * 32];
  __shared__ unsigned short B1s[128 * 32];
  __shared__ unsigned short B3s[128 * 32];

  const int tid = threadIdx.x;
  const int kcol = (tid & 3) * 8;
  const int r0 = tid >> 2;
  const int r1 = r0 + 64;
  int mr0 = m0 + r0; if (mr0 > count - 1) mr0 = count - 1;
  int mr1 = m0 + r1; if (mr1 > count - 1) mr1 = count - 1;
  const int tok0 = rows[sbase + mr0];
  const int tok1 = rows[sbase + mr1];
  const unsigned short* pA0 = xb + (size_t)tok0 * DDIM + kcol;
  const unsigned short* pA1 = xb + (size_t)tok1 * DDIM + kcol;
  const unsigned short* pB10 = w1t + ((size_t)e * FDIM + n0 + r0) * DDIM + kcol;
  const unsigned short* pB11 = w1t + ((size_t)e * FDIM + n0 + r1) * DDIM + kcol;
  const unsigned short* pB30 = w3t + ((size_t)e * FDIM + n0 + r0) * DDIM + kcol;
  const unsigned short* pB31 = w3t + ((size_t)e * FDIM + n0 + r1) * DDIM + kcol;
  unsigned short* lA0 = &As[tid * 8];
  unsigned short* lA1 = &As[tid * 8 + 2048];
  unsigned short* lB10 = &B1s[tid * 8];
  unsigned short* lB11 = &B1s[tid * 8 + 2048];
  unsigned short* lB30 = &B3s[tid * 8];
  unsigned short* lB31 = &B3s[tid * 8 + 2048];

  const int wv = tid >> 6;
  const int wr = (wv >> 1) * 64;
  const int wc = (wv & 1) * 64;
  const int lane = tid & 63;
  const int q8 = (lane >> 4) * 8;
  const int lm = lane & 15;

  f32x4 acc1[4][4], acc3[4][4];
#pragma unroll
  for (int i = 0; i < 4; i++)
#pragma unroll
    for (int j = 0; j < 4; j++) {
      acc1[i][j] = f32x4{0.f, 0.f, 0.f, 0.f};
      acc3[i][j] = f32x4{0.f, 0.f, 0.f, 0.f};
    }

  for (int kt = 0; kt < DDIM; kt += 32) {
    __syncthreads();
    async_cp16(pA0 + kt, lA0);
    async_cp16(pA1 + kt, lA1);
    async_cp16(pB10 + kt, lB10);
    async_cp16(pB11 + kt, lB11);
    async_cp16(pB30 + kt, lB30);
    async_cp16(pB31 + kt, lB31);
    __syncthreads();

    bf16x8 a[4], b1[4], b3[4];
#pragma unroll
    for (int i = 0; i < 4; i++)
      a[i] = *(const bf16x8*)&As[(wr + i * 16 + lm) * 32 + q8];
#pragma unroll
    for (int j = 0; j < 4; j++) {
      b1[j] = *(const bf16x8*)&B1s[(wc + j * 16 + lm) * 32 + q8];
      b3[j] = *(const bf16x8*)&B3s[(wc + j * 16 + lm) * 32 + q8];
    }
#pragma unroll
    for (int i = 0; i < 4; i++)
#pragma unroll
      for (int j = 0; j < 4; j++) {
        acc1[i][j] = __builtin_amdgcn_mfma_f32_16x16x32_bf16(a[i], b1[j], acc1[i][j], 0, 0, 0);
        acc3[i][j] = __builtin_amdgcn_mfma_f32_16x16x32_bf16(a[i], b3[j], acc3[i][j], 0, 0, 0);
      }
  }

#pragma unroll
  for (int i = 0; i < 4; i++) {
#pragma unroll
    for (int r = 0; r < 4; r++) {
      int ml = wr + i * 16 + (lane >> 4) * 4 + r;
      int mg = m0 + ml;
      if (mg < count) {
        unsigned short* hp = h + (size_t)(sbase + mg) * FDIM + n0 + wc + lm;
#pragma unroll
        for (int j = 0; j < 4; j++) {
          float v1 = acc1[i][j][r];
          float v3 = acc3[i][j][r];
          float hv = (v1 / (1.0f + __expf(-v1))) * v3;
          hp[j * 16] = f2bf(hv);
        }
      }
    }
  }
}

// ---------------- GEMM2: out[tok] += p * (h @ w2) ----------------
__global__ __launch_bounds__(256) void gemm2_kernel(
    const unsigned short* __restrict__ h,    // [T*2][F] bf16
    const unsigned short* __restrict__ w2t,  // [E][D][F] bf16
    const int* __restrict__ rows,
    const float* __restrict__ pslot,
    const int* __restrict__ hdr,
    float* __restrict__ out)                 // [T][D] fp32 (zeroed)
{
  const int e = blockIdx.z;
  const int count = hdr[e];
  const int m0 = blockIdx.y * 128;
  if (m0 >= count) return;
  const int n0 = blockIdx.x * 128;
  const int sbase = hdr[16 + e];

  __shared__ unsigned short As[128 * 32];
  __shared__ unsigned short Bs[128 * 32];
  __shared__ int tokl[128];
  __shared__ float pl[128];

  const int tid = threadIdx.x;
  const int kcol = (tid & 3) * 8;
  const int r0 = tid >> 2;
  const int r1 = r0 + 64;
  int mr0 = m0 + r0; if (mr0 > count - 1) mr0 = count - 1;
  int mr1 = m0 + r1; if (mr1 > count - 1) mr1 = count - 1;
  const unsigned short* pA0 = h + (size_t)(sbase + mr0) * FDIM + kcol;
  const unsigned short* pA1 = h + (size_t)(sbase + mr1) * FDIM + kcol;
  const unsigned short* pB0 = w2t + ((size_t)e * DDIM + n0 + r0) * FDIM + kcol;
  const unsigned short* pB1 = w2t + ((size_t)e * DDIM + n0 + r1) * FDIM + kcol;
  unsigned short* lA0 = &As[tid * 8];
  unsigned short* lA1 = &As[tid * 8 + 2048];
  unsigned short* lB0 = &Bs[tid * 8];
  unsigned short* lB1 = &Bs[tid * 8 + 2048];

  if (tid < 128) {
    int mr = m0 + tid; if (mr > count - 1) mr = count - 1;
    tokl[tid] = rows[sbase + mr];
    pl[tid] = pslot[sbase + mr];
  }

  const int wv = tid >> 6;
  const int wr = (wv >> 1) * 64;
  const int wc = (wv & 1) * 64;
  const int lane = tid & 63;
  const int q8 = (lane >> 4) * 8;
  const int lm = lane & 15;

  f32x4 acc[4][4];
#pragma unroll
  for (int i = 0; i < 4; i++)
#pragma unroll
    for (int j = 0; j < 4; j++) acc[i][j] = f32x4{0.f, 0.f, 0.f, 0.f};

  for (int kt = 0; kt < FDIM; kt += 32) {
    __syncthreads();
    async_cp16(pA0 + kt, lA0);
    async_cp16(pA1 + kt, lA1);
    async_cp16(pB0 + kt, lB0);
    async_cp16(pB1 + kt, lB1);
    __syncthreads();

    bf16x8 a[4], b[4];
#pragma unroll
    for (int i = 0; i < 4; i++)
      a[i] = *(const bf16x8*)&As[(wr + i * 16 + lm) * 32 + q8];
#pragma unroll
    for (int j = 0; j < 4; j++)
      b[j] = *(const bf16x8*)&Bs[(wc + j * 16 + lm) * 32 + q8];
#pragma unroll
    for (int i = 0; i < 4; i++)
#pragma unroll
      for (int j = 0; j < 4; j++)
        acc[i][j] = __builtin_amdgcn_mfma_f32_16x16x32_bf16(a[i], b[j], acc[i][j], 0, 0, 0);
  }

#pragma unroll
  for (int i = 0; i < 4; i++) {
#pragma unroll
    for (int r = 0; r < 4; r++) {
      int ml = wr + i * 16 + (lane >> 4) * 4 + r;
      if (m0 + ml < count) {
        int t = tokl[ml];
        float p = pl[ml];
        float* op = out + (size_t)t * DDIM + n0 + wc + lm;
#pragma unroll
        for (int j = 0; j < 4; j++) atomicAdd(&op[j * 16], p * acc[i][j][r]);
      }
    }
  }
}

extern "C" void kernel_launch(void* const* d_in, const int* in_sizes, int n_in,
                              void* d_out, int out_size, void* d_ws, size_t ws_size,
                              hipStream_t stream) {
  const float* x  = (const float*)d_in[0];
  const float* wg = (const float*)d_in[1];
  const float* w1 = (const float*)d_in[2];
  const float* w3 = (const float*)d_in[3];
  const float* w2 = (const float*)d_in[4];
  float* out = (float*)d_out;
  char* ws = (char*)d_ws;

  size_t off = 0;
  int* hdr = (int*)(ws + off); off += 256;
  int* sel = (int*)(ws + off); off += (size_t)T_TOK * 2 * 4;
  float* prb = (float*)(ws + off); off += (size_t)T_TOK * 2 * 4;
  int* rows = (int*)(ws + off); off += (size_t)T_TOK * 2 * 4;
  float* pslot = (float*)(ws + off); off += (size_t)T_TOK * 2 * 4;
  unsigned short* xb  = (unsigned short*)(ws + off); off += (size_t)T_TOK * DDIM * 2;
  unsigned short* w1t = (unsigned short*)(ws + off); off += (size_t)EEXP * DDIM * FDIM * 2;
  unsigned short* w3t = (unsigned short*)(ws + off); off += (size_t)EEXP * DDIM * FDIM * 2;
  unsigned short* w2t = (unsigned short*)(ws + off); off += (size_t)EEXP * DDIM * FDIM * 2;
  unsigned short* h   = (unsigned short*)(ws + off); off += (size_t)T_TOK * 2 * FDIM * 2;

  hipMemsetAsync(hdr, 0, 256, stream);
  hipMemsetAsync(d_out, 0, (size_t)T_TOK * DDIM * 4, stream);

  castx_kernel<<<T_TOK * DDIM / 4 / 256, 256, 0, stream>>>(x, xb, T_TOK * DDIM / 4);
  transpose_cast_kernel<<<dim3(FDIM / 32, DDIM / 32, EEXP), dim3(32, 8), 0, stream>>>(w1, w1t, DDIM, FDIM);
  transpose_cast_kernel<<<dim3(FDIM / 32, DDIM / 32, EEXP), dim3(32, 8), 0, stream>>>(w3, w3t, DDIM, FDIM);
  transpose_cast_kernel<<<dim3(DDIM / 32, FDIM / 32, EEXP), dim3(32, 8), 0, stream>>>(w2, w2t, FDIM, DDIM);
  gate_kernel<<<T_TOK / 4, 256, 0, stream>>>(x, wg, sel, prb, hdr);
  scan_kernel<<<1, 64, 0, stream>>>(hdr);
  build_kernel<<<(T_TOK * 2 + 255) / 256, 256, 0, stream>>>(sel, prb, hdr, rows, pslot);
  gemm1_kernel<<<dim3(FDIM / 128, T_TOK / 128, EEXP), 256, 0, stream>>>(xb, w1t, w3t, rows, hdr, h);
  gemm2_kernel<<<dim3(DDIM / 128, T_TOK / 128, EEXP), 256, 0, stream>>>(h, w2t, rows, pslot, hdr, out);
}

// Round 2
// 997.653 us; speedup vs baseline: 1.0219x; 1.0219x over previous
//
#include <hip/hip_runtime.h>
#include <stdint.h>

#define T_TOK 8192
#define DDIM 1024
#define EEXP 8
#define FDIM 2048

typedef float f32x4 __attribute__((ext_vector_type(4)));
typedef __bf16 bf16x8 __attribute__((ext_vector_type(8)));

__device__ __forceinline__ unsigned short f2bf(float f) {
  union { float f; unsigned int u; } v; v.f = f;
  unsigned int r = (v.u + 0x7fffu + ((v.u >> 16) & 1u)) >> 16;
  return (unsigned short)r;
}

__device__ __forceinline__ void async_cp16(const void* g, void* l) {
  __builtin_amdgcn_global_load_lds(
      (const __attribute__((address_space(1))) unsigned int*)g,
      (__attribute__((address_space(3))) unsigned int*)l, 16, 0, 0);
}

// ---------------- cast x fp32 -> bf16 ----------------
__global__ __launch_bounds__(256) void castx_kernel(const float* __restrict__ in,
                                                    unsigned short* __restrict__ out,
                                                    int n4) {
  int i = blockIdx.x * 256 + threadIdx.x;
  if (i >= n4) return;
  float4 v = ((const float4*)in)[i];
  ushort4 o;
  o.x = f2bf(v.x); o.y = f2bf(v.y); o.z = f2bf(v.z); o.w = f2bf(v.w);
  ((ushort4*)out)[i] = o;
}

// ---------------- transpose-cast weights: in [e][R][C] fp32 -> out [e][C][R] bf16 ----
// 64x64 tile, block (64,4). Conflict-free 65-stride LDS.
__global__ __launch_bounds__(256) void transpose_cast_kernel(const float* __restrict__ in,
                                                             unsigned short* __restrict__ out,
                                                             int R, int C) {
  __shared__ float tile[64][65];
  const size_t ebase = (size_t)blockIdx.z * R * C;
  int c0 = blockIdx.x * 64;
  int r0 = blockIdx.y * 64;
  int tx = threadIdx.x;
  int ty = threadIdx.y;
#pragma unroll
  for (int i = 0; i < 64; i += 4)
    tile[ty + i][tx] = in[ebase + (size_t)(r0 + ty + i) * C + c0 + tx];
  __syncthreads();
#pragma unroll
  for (int i = 0; i < 64; i += 4)
    out[ebase + (size_t)(c0 + ty + i) * R + r0 + tx] = f2bf(tile[tx][ty + i]);
}

// ---------------- gating: wave per token ----------------
// hdr layout (ints): [0..7]=cnt, [8..15]=fill, [16..24]=offs
__global__ __launch_bounds__(256) void gate_kernel(const float* __restrict__ x,
                                                   const float* __restrict__ wg,
                                                   int* __restrict__ sel,
                                                   float* __restrict__ prb,
                                                   int* __restrict__ hdr) {
  __shared__ float wgs[8 * 1024];  // transposed [e][d]
  int tid = threadIdx.x;
  for (int i = tid; i < 8192; i += 256) {
    int d = i >> 3, e = i & 7;
    wgs[e * 1024 + d] = wg[i];
  }
  __syncthreads();
  int lane = tid & 63;
  int t = blockIdx.x * 4 + (tid >> 6);
  const float* xr = x + (size_t)t * 1024;
  float acc[8] = {0.f, 0.f, 0.f, 0.f, 0.f, 0.f, 0.f, 0.f};
  for (int d = lane; d < 1024; d += 64) {
    float xv = xr[d];
#pragma unroll
    for (int e = 0; e < 8; e++) acc[e] += xv * wgs[e * 1024 + d];
  }
#pragma unroll
  for (int e = 0; e < 8; e++) {
    acc[e] += __shfl_xor(acc[e], 32);
    acc[e] += __shfl_xor(acc[e], 16);
    acc[e] += __shfl_xor(acc[e], 8);
    acc[e] += __shfl_xor(acc[e], 4);
    acc[e] += __shfl_xor(acc[e], 2);
    acc[e] += __shfl_xor(acc[e], 1);
  }
  if (lane == 0) {
    int i0 = 0; float v0 = acc[0];
#pragma unroll
    for (int e = 1; e < 8; e++) if (acc[e] > v0) { v0 = acc[e]; i0 = e; }
    int i1 = -1; float v1 = -1e30f;
#pragma unroll
    for (int e = 0; e < 8; e++) if (e != i0 && acc[e] > v1) { v1 = acc[e]; i1 = e; }
    float ex = __expf(v1 - v0);
    float inv = 1.0f / (1.0f + ex);
    sel[t * 2] = i0; sel[t * 2 + 1] = i1;
    prb[t * 2] = inv; prb[t * 2 + 1] = ex * inv;
    atomicAdd(&hdr[i0], 1);
    atomicAdd(&hdr[i1], 1);
  }
}

__global__ void scan_kernel(int* hdr) {
  if (threadIdx.x == 0 && blockIdx.x == 0) {
    int s = 0;
    for (int e = 0; e < 8; e++) { hdr[16 + e] = s; s += hdr[e]; }
    hdr[24] = s;
  }
}

__global__ __launch_bounds__(256) void build_kernel(const int* __restrict__ sel,
                                                    const float* __restrict__ prb,
                                                    int* __restrict__ hdr,
                                                    int* __restrict__ rows,
                                                    int* __restrict__ slot_of) {
  int i = blockIdx.x * 256 + threadIdx.x;
  if (i >= T_TOK * 2) return;
  int e = sel[i];
  int pos = hdr[16 + e] + atomicAdd(&hdr[8 + e], 1);
  rows[pos] = i >> 1;
  slot_of[i] = pos;
}

// ---------------- GEMM1: h = silu(x@w1) * (x@w3), gathered rows, double-buffered ----
__global__ __launch_bounds__(256) void gemm1_kernel(
    const unsigned short* __restrict__ xb,   // [T][D] bf16
    const unsigned short* __restrict__ w1t,  // [E][F][D] bf16
    const unsigned short* __restrict__ w3t,  // [E][F][D] bf16
    const int* __restrict__ rows,            // slot -> token
    const int* __restrict__ hdr,
    unsigned short* __restrict__ h)          // [T*2][F] bf16 (slot space)
{
  const int e = blockIdx.z;
  const int count = hdr[e];
  const int m0 = blockIdx.y * 128;
  if (m0 >= count) return;
  const int n0 = blockIdx.x * 128;
  const int sbase = hdr[16 + e];

  __shared__ unsigned short As[2][4096];
  __shared__ unsigned short B1s[2][4096];
  __shared__ unsigned short B3s[2][4096];

  const int tid = threadIdx.x;
  const int kcol = (tid & 3) * 8;
  const int r0 = tid >> 2;
  int mr0 = m0 + r0;      if (mr0 > count - 1) mr0 = count - 1;
  int mr1 = m0 + r0 + 64; if (mr1 > count - 1) mr1 = count - 1;
  const int tok0 = rows[sbase + mr0];
  const int tok1 = rows[sbase + mr1];
  const unsigned short* pA0 = xb + (size_t)tok0 * DDIM + kcol;
  const unsigned short* pA1 = xb + (size_t)tok1 * DDIM + kcol;
  const unsigned short* pB10 = w1t + ((size_t)e * FDIM + n0 + r0) * DDIM + kcol;
  const unsigned short* pB11 = w1t + ((size_t)e * FDIM + n0 + r0 + 64) * DDIM + kcol;
  const unsigned short* pB30 = w3t + ((size_t)e * FDIM + n0 + r0) * DDIM + kcol;
  const unsigned short* pB31 = w3t + ((size_t)e * FDIM + n0 + r0 + 64) * DDIM + kcol;
  const int l0 = tid * 8;
  const int l1 = tid * 8 + 2048;

  const int wv = tid >> 6;
  const int wr = (wv >> 1) * 64;
  const int wc = (wv & 1) * 64;
  const int lane = tid & 63;
  const int q8 = (lane >> 4) * 8;
  const int lm = lane & 15;

  f32x4 acc1[4][4], acc3[4][4];
#pragma unroll
  for (int i = 0; i < 4; i++)
#pragma unroll
    for (int j = 0; j < 4; j++) {
      acc1[i][j] = f32x4{0.f, 0.f, 0.f, 0.f};
      acc3[i][j] = f32x4{0.f, 0.f, 0.f, 0.f};
    }

  // prologue: stage tile 0 into buffer 0
  async_cp16(pA0, &As[0][l0]);
  async_cp16(pA1, &As[0][l1]);
  async_cp16(pB10, &B1s[0][l0]);
  async_cp16(pB11, &B1s[0][l1]);
  async_cp16(pB30, &B3s[0][l0]);
  async_cp16(pB31, &B3s[0][l1]);

  for (int kt = 0; kt < DDIM; kt += 32) {
    const int cur = (kt >> 5) & 1;
    __syncthreads();  // vmcnt(0) drain: tile kt (issued one compute-phase ago) is ready
    if (kt + 32 < DDIM) {
      const int nxt = cur ^ 1;
      async_cp16(pA0 + kt + 32, &As[nxt][l0]);
      async_cp16(pA1 + kt + 32, &As[nxt][l1]);
      async_cp16(pB10 + kt + 32, &B1s[nxt][l0]);
      async_cp16(pB11 + kt + 32, &B1s[nxt][l1]);
      async_cp16(pB30 + kt + 32, &B3s[nxt][l0]);
      async_cp16(pB31 + kt + 32, &B3s[nxt][l1]);
    }

    bf16x8 a[4], b1[4], b3[4];
#pragma unroll
    for (int i = 0; i < 4; i++)
      a[i] = *(const bf16x8*)&As[cur][(wr + i * 16 + lm) * 32 + q8];
#pragma unroll
    for (int j = 0; j < 4; j++) {
      b1[j] = *(const bf16x8*)&B1s[cur][(wc + j * 16 + lm) * 32 + q8];
      b3[j] = *(const bf16x8*)&B3s[cur][(wc + j * 16 + lm) * 32 + q8];
    }
#pragma unroll
    for (int i = 0; i < 4; i++)
#pragma unroll
      for (int j = 0; j < 4; j++) {
        acc1[i][j] = __builtin_amdgcn_mfma_f32_16x16x32_bf16(a[i], b1[j], acc1[i][j], 0, 0, 0);
        acc3[i][j] = __builtin_amdgcn_mfma_f32_16x16x32_bf16(a[i], b3[j], acc3[i][j], 0, 0, 0);
      }
  }

#pragma unroll
  for (int i = 0; i < 4; i++) {
#pragma unroll
    for (int r = 0; r < 4; r++) {
      int ml = wr + i * 16 + (lane >> 4) * 4 + r;
      int mg = m0 + ml;
      if (mg < count) {
        unsigned short* hp = h + (size_t)(sbase + mg) * FDIM + n0 + wc + lm;
#pragma unroll
        for (int j = 0; j < 4; j++) {
          float v1 = acc1[i][j][r];
          float v3 = acc3[i][j][r];
          float hv = (v1 / (1.0f + __expf(-v1))) * v3;
          hp[j * 16] = f2bf(hv);
        }
      }
    }
  }
}

// ---------------- GEMM2: y[slot] = h[slot] @ w2, double-buffered, no atomics ------
__global__ __launch_bounds__(256) void gemm2_kernel(
    const unsigned short* __restrict__ h,    // [T*2][F] bf16
    const unsigned short* __restrict__ w2t,  // [E][D][F] bf16
    const int* __restrict__ hdr,
    float* __restrict__ y)                   // [T*2][D] fp32 (slot space)
{
  const int e = blockIdx.z;
  const int count = hdr[e];
  const int m0 = blockIdx.y * 128;
  if (m0 >= count) return;
  const int n0 = blockIdx.x * 128;
  const int sbase = hdr[16 + e];

  __shared__ unsigned short Ahs[2][4096];
  __shared__ unsigned short Bs[2][4096];

  const int tid = threadIdx.x;
  const int kcol = (tid & 3) * 8;
  const int r0 = tid >> 2;
  int mr0 = m0 + r0;      if (mr0 > count - 1) mr0 = count - 1;
  int mr1 = m0 + r0 + 64; if (mr1 > count - 1) mr1 = count - 1;
  const unsigned short* pA0 = h + (size_t)(sbase + mr0) * FDIM + kcol;
  const unsigned short* pA1 = h + (size_t)(sbase + mr1) * FDIM + kcol;
  const unsigned short* pB0 = w2t + ((size_t)e * DDIM + n0 + r0) * FDIM + kcol;
  const unsigned short* pB1 = w2t + ((size_t)e * DDIM + n0 + r0 + 64) * FDIM + kcol;
  const int l0 = tid * 8;
  const int l1 = tid * 8 + 2048;

  const int wv = tid >> 6;
  const int wr = (wv >> 1) * 64;
  const int wc = (wv & 1) * 64;
  const int lane = tid & 63;
  const int q8 = (lane >> 4) * 8;
  const int lm = lane & 15;

  f32x4 acc[4][4];
#pragma unroll
  for (int i = 0; i < 4; i++)
#pragma unroll
    for (int j = 0; j < 4; j++) acc[i][j] = f32x4{0.f, 0.f, 0.f, 0.f};

  async_cp16(pA0, &Ahs[0][l0]);
  async_cp16(pA1, &Ahs[0][l1]);
  async_cp16(pB0, &Bs[0][l0]);
  async_cp16(pB1, &Bs[0][l1]);

  for (int kt = 0; kt < FDIM; kt += 32) {
    const int cur = (kt >> 5) & 1;
    __syncthreads();
    if (kt + 32 < FDIM) {
      const int nxt = cur ^ 1;
      async_cp16(pA0 + kt + 32, &Ahs[nxt][l0]);
      async_cp16(pA1 + kt + 32, &Ahs[nxt][l1]);
      async_cp16(pB0 + kt + 32, &Bs[nxt][l0]);
      async_cp16(pB1 + kt + 32, &Bs[nxt][l1]);
    }

    bf16x8 a[4], b[4];
#pragma unroll
    for (int i = 0; i < 4; i++)
      a[i] = *(const bf16x8*)&Ahs[cur][(wr + i * 16 + lm) * 32 + q8];
#pragma unroll
    for (int j = 0; j < 4; j++)
      b[j] = *(const bf16x8*)&Bs[cur][(wc + j * 16 + lm) * 32 + q8];
#pragma unroll
    for (int i = 0; i < 4; i++)
#pragma unroll
      for (int j = 0; j < 4; j++)
        acc[i][j] = __builtin_amdgcn_mfma_f32_16x16x32_bf16(a[i], b[j], acc[i][j], 0, 0, 0);
  }

#pragma unroll
  for (int i = 0; i < 4; i++) {
#pragma unroll
    for (int r = 0; r < 4; r++) {
      int ml = wr + i * 16 + (lane >> 4) * 4 + r;
      int mg = m0 + ml;
      if (mg < count) {
        float* yp = y + (size_t)(sbase + mg) * DDIM + n0 + wc + lm;
#pragma unroll
        for (int j = 0; j < 4; j++) yp[j * 16] = acc[i][j][r];
      }
    }
  }
}

// ---------------- combine: out[t] = p0*y[s0] + p1*y[s1] ----------------
__global__ __launch_bounds__(256) void combine_kernel(const float* __restrict__ y,
                                                      const int* __restrict__ slot_of,
                                                      const float* __restrict__ prb,
                                                      float* __restrict__ out) {
  int t = blockIdx.x;
  int s0 = slot_of[t * 2], s1 = slot_of[t * 2 + 1];
  float p0 = prb[t * 2], p1 = prb[t * 2 + 1];
  float4 a = ((const float4*)(y + (size_t)s0 * DDIM))[threadIdx.x];
  float4 b = ((const float4*)(y + (size_t)s1 * DDIM))[threadIdx.x];
  float4 o;
  o.x = p0 * a.x + p1 * b.x;
  o.y = p0 * a.y + p1 * b.y;
  o.z = p0 * a.z + p1 * b.z;
  o.w = p0 * a.w + p1 * b.w;
  ((float4*)(out + (size_t)t * DDIM))[threadIdx.x] = o;
}

extern "C" void kernel_launch(void* const* d_in, const int* in_sizes, int n_in,
                              void* d_out, int out_size, void* d_ws, size_t ws_size,
                              hipStream_t stream) {
  const float* x  = (const float*)d_in[0];
  const float* wg = (const float*)d_in[1];
  const float* w1 = (const float*)d_in[2];
  const float* w3 = (const float*)d_in[3];
  const float* w2 = (const float*)d_in[4];
  float* out = (float*)d_out;
  char* ws = (char*)d_ws;

  size_t off = 0;
  int* hdr = (int*)(ws + off); off += 256;
  int* sel = (int*)(ws + off); off += (size_t)T_TOK * 2 * 4;
  float* prb = (float*)(ws + off); off += (size_t)T_TOK * 2 * 4;
  int* rows = (int*)(ws + off); off += (size_t)T_TOK * 2 * 4;
  int* slot_of = (int*)(ws + off); off += (size_t)T_TOK * 2 * 4;
  unsigned short* xb  = (unsigned short*)(ws + off); off += (size_t)T_TOK * DDIM * 2;
  unsigned short* w1t = (unsigned short*)(ws + off); off += (size_t)EEXP * DDIM * FDIM * 2;
  unsigned short* w3t = (unsigned short*)(ws + off); off += (size_t)EEXP * DDIM * FDIM * 2;
  unsigned short* w2t = (unsigned short*)(ws + off); off += (size_t)EEXP * DDIM * FDIM * 2;
  unsigned short* h   = (unsigned short*)(ws + off); off += (size_t)T_TOK * 2 * FDIM * 2;
  // y overlays w1t+w3t (64 MB, dead after gemm1): [T*2][D] fp32
  float* y = (float*)w1t;

  hipMemsetAsync(hdr, 0, 256, stream);

  castx_kernel<<<T_TOK * DDIM / 4 / 256, 256, 0, stream>>>(x, xb, T_TOK * DDIM / 4);
  transpose_cast_kernel<<<dim3(FDIM / 64, DDIM / 64, EEXP), dim3(64, 4), 0, stream>>>(w1, w1t, DDIM, FDIM);
  transpose_cast_kernel<<<dim3(FDIM / 64, DDIM / 64, EEXP), dim3(64, 4), 0, stream>>>(w3, w3t, DDIM, FDIM);
  transpose_cast_kernel<<<dim3(DDIM / 64, FDIM / 64, EEXP), dim3(64, 4), 0, stream>>>(w2, w2t, FDIM, DDIM);
  gate_kernel<<<T_TOK / 4, 256, 0, stream>>>(x, wg, sel, prb, hdr);
  scan_kernel<<<1, 64, 0, stream>>>(hdr);
  build_kernel<<<(T_TOK * 2 + 255) / 256, 256, 0, stream>>>(sel, prb, hdr, rows, slot_of);
  gemm1_kernel<<<dim3(FDIM / 128, T_TOK / 128, EEXP), 256, 0, stream>>>(xb, w1t, w3t, rows, hdr, h);
  gemm2_kernel<<<dim3(DDIM / 128, T_TOK / 128, EEXP), 256, 0, stream>>>(h, w2t, hdr, y);
  combine_kernel<<<T_TOK, 256, 0, stream>>>(y, slot_of, prb, out);
}

// Round 3
// 858.194 us; speedup vs baseline: 1.1880x; 1.1625x over previous
//
#include <hip/hip_runtime.h>
#include <stdint.h>

#define T_TOK 8192
#define DDIM 1024
#define EEXP 8
#define FDIM 2048

typedef float f32x4 __attribute__((ext_vector_type(4)));
typedef __bf16 bf16x8 __attribute__((ext_vector_type(8)));

__device__ __forceinline__ unsigned short f2bf(float f) {
  union { float f; unsigned int u; } v; v.f = f;
  unsigned int r = (v.u + 0x7fffu + ((v.u >> 16) & 1u)) >> 16;
  return (unsigned short)r;
}

__device__ __forceinline__ void async_cp16(const void* g, void* l) {
  __builtin_amdgcn_global_load_lds(
      (const __attribute__((address_space(1))) unsigned int*)g,
      (__attribute__((address_space(3))) unsigned int*)l, 16, 0, 0);
}

// ---------------- cast x fp32 -> bf16 ----------------
__global__ __launch_bounds__(256) void castx_kernel(const float* __restrict__ in,
                                                    unsigned short* __restrict__ out,
                                                    int n4) {
  int i = blockIdx.x * 256 + threadIdx.x;
  if (i >= n4) return;
  float4 v = ((const float4*)in)[i];
  ushort4 o;
  o.x = f2bf(v.x); o.y = f2bf(v.y); o.z = f2bf(v.z); o.w = f2bf(v.w);
  ((ushort4*)out)[i] = o;
}

// ---------------- transpose-cast weights: in [e][R][C] fp32 -> out [e][C][R] bf16 ----
__global__ __launch_bounds__(256) void transpose_cast_kernel(const float* __restrict__ in,
                                                             unsigned short* __restrict__ out,
                                                             int R, int C) {
  __shared__ float tile[64][65];
  const size_t ebase = (size_t)blockIdx.z * R * C;
  int c0 = blockIdx.x * 64;
  int r0 = blockIdx.y * 64;
  int tx = threadIdx.x;
  int ty = threadIdx.y;
#pragma unroll
  for (int i = 0; i < 64; i += 4)
    tile[ty + i][tx] = in[ebase + (size_t)(r0 + ty + i) * C + c0 + tx];
  __syncthreads();
#pragma unroll
  for (int i = 0; i < 64; i += 4)
    out[ebase + (size_t)(c0 + ty + i) * R + r0 + tx] = f2bf(tile[tx][ty + i]);
}

// ---------------- gating: wave per token ----------------
// hdr layout (ints): [0..7]=cnt, [8..15]=fill, [16..24]=offs
__global__ __launch_bounds__(256) void gate_kernel(const float* __restrict__ x,
                                                   const float* __restrict__ wg,
                                                   int* __restrict__ sel,
                                                   float* __restrict__ prb,
                                                   int* __restrict__ hdr) {
  __shared__ float wgs[8 * 1024];  // transposed [e][d]
  int tid = threadIdx.x;
  for (int i = tid; i < 8192; i += 256) {
    int d = i >> 3, e = i & 7;
    wgs[e * 1024 + d] = wg[i];
  }
  __syncthreads();
  int lane = tid & 63;
  int t = blockIdx.x * 4 + (tid >> 6);
  const float* xr = x + (size_t)t * 1024;
  float acc[8] = {0.f, 0.f, 0.f, 0.f, 0.f, 0.f, 0.f, 0.f};
  for (int d = lane; d < 1024; d += 64) {
    float xv = xr[d];
#pragma unroll
    for (int e = 0; e < 8; e++) acc[e] += xv * wgs[e * 1024 + d];
  }
#pragma unroll
  for (int e = 0; e < 8; e++) {
    acc[e] += __shfl_xor(acc[e], 32);
    acc[e] += __shfl_xor(acc[e], 16);
    acc[e] += __shfl_xor(acc[e], 8);
    acc[e] += __shfl_xor(acc[e], 4);
    acc[e] += __shfl_xor(acc[e], 2);
    acc[e] += __shfl_xor(acc[e], 1);
  }
  if (lane == 0) {
    int i0 = 0; float v0 = acc[0];
#pragma unroll
    for (int e = 1; e < 8; e++) if (acc[e] > v0) { v0 = acc[e]; i0 = e; }
    int i1 = -1; float v1 = -1e30f;
#pragma unroll
    for (int e = 0; e < 8; e++) if (e != i0 && acc[e] > v1) { v1 = acc[e]; i1 = e; }
    float ex = __expf(v1 - v0);
    float inv = 1.0f / (1.0f + ex);
    sel[t * 2] = i0; sel[t * 2 + 1] = i1;
    prb[t * 2] = inv; prb[t * 2 + 1] = ex * inv;
    atomicAdd(&hdr[i0], 1);
    atomicAdd(&hdr[i1], 1);
  }
}

__global__ void scan_kernel(int* hdr) {
  if (threadIdx.x == 0 && blockIdx.x == 0) {
    int s = 0;
    for (int e = 0; e < 8; e++) { hdr[16 + e] = s; s += hdr[e]; }
    hdr[24] = s;
  }
}

__global__ __launch_bounds__(256) void build_kernel(const int* __restrict__ sel,
                                                    const float* __restrict__ prb,
                                                    int* __restrict__ hdr,
                                                    int* __restrict__ rows,
                                                    int* __restrict__ slot_of) {
  int i = blockIdx.x * 256 + threadIdx.x;
  if (i >= T_TOK * 2) return;
  int e = sel[i];
  int pos = hdr[16 + e] + atomicAdd(&hdr[8 + e], 1);
  rows[pos] = i >> 1;
  slot_of[i] = pos;
}

// ---------------- GEMM1: h = silu(x@w1)*(x@w3) ------------------------------
// Block tile 128(M) x 64(N), 4 waves in 2x2, wave tile 64x32 per B matrix.
// acc = 16 f32x4 = 64 AGPR; launch_bounds(256,3) -> 3 waves/SIMD.
__global__ __launch_bounds__(256, 3) void gemm1_kernel(
    const unsigned short* __restrict__ xb,   // [T][D] bf16
    const unsigned short* __restrict__ w1t,  // [E][F][D] bf16
    const unsigned short* __restrict__ w3t,  // [E][F][D] bf16
    const int* __restrict__ rows,            // slot -> token
    const int* __restrict__ hdr,
    unsigned short* __restrict__ h)          // [T*2][F] bf16 (slot space)
{
  const int e = blockIdx.z;
  const int count = hdr[e];
  const int m0 = blockIdx.y * 128;
  if (m0 >= count) return;
  const int n0 = blockIdx.x * 64;
  const int sbase = hdr[16 + e];

  __shared__ unsigned short As[2][4096];   // 128 x 32
  __shared__ unsigned short B1s[2][2048];  // 64 x 32
  __shared__ unsigned short B3s[2][2048];  // 64 x 32

  const int tid = threadIdx.x;
  const int kcol = (tid & 3) * 8;
  const int r0 = tid >> 2;                 // 0..63
  int mr0 = m0 + r0;      if (mr0 > count - 1) mr0 = count - 1;
  int mr1 = m0 + r0 + 64; if (mr1 > count - 1) mr1 = count - 1;
  const int tok0 = rows[sbase + mr0];
  const int tok1 = rows[sbase + mr1];
  const unsigned short* pA0 = xb + (size_t)tok0 * DDIM + kcol;
  const unsigned short* pA1 = xb + (size_t)tok1 * DDIM + kcol;
  const unsigned short* pB1 = w1t + ((size_t)e * FDIM + n0 + r0) * DDIM + kcol;
  const unsigned short* pB3 = w3t + ((size_t)e * FDIM + n0 + r0) * DDIM + kcol;
  const int l0 = tid * 8;

  const int wv = tid >> 6;
  const int wr = (wv >> 1) * 64;           // 0 / 64
  const int wc = (wv & 1) * 32;            // 0 / 32
  const int lane = tid & 63;
  const int q8 = (lane >> 4) * 8;
  const int lm = lane & 15;

  f32x4 acc1[4][2], acc3[4][2];
#pragma unroll
  for (int i = 0; i < 4; i++)
#pragma unroll
    for (int j = 0; j < 2; j++) {
      acc1[i][j] = f32x4{0.f, 0.f, 0.f, 0.f};
      acc3[i][j] = f32x4{0.f, 0.f, 0.f, 0.f};
    }

  // prologue: stage tile 0 into buffer 0
  async_cp16(pA0, &As[0][l0]);
  async_cp16(pA1, &As[0][l0 + 2048]);
  async_cp16(pB1, &B1s[0][l0]);
  async_cp16(pB3, &B3s[0][l0]);

  for (int kt = 0; kt < DDIM; kt += 32) {
    const int cur = (kt >> 5) & 1;
    __syncthreads();
    if (kt + 32 < DDIM) {
      const int nxt = cur ^ 1;
      async_cp16(pA0 + kt + 32, &As[nxt][l0]);
      async_cp16(pA1 + kt + 32, &As[nxt][l0 + 2048]);
      async_cp16(pB1 + kt + 32, &B1s[nxt][l0]);
      async_cp16(pB3 + kt + 32, &B3s[nxt][l0]);
    }

    bf16x8 a[4], b1[2], b3[2];
#pragma unroll
    for (int i = 0; i < 4; i++)
      a[i] = *(const bf16x8*)&As[cur][(wr + i * 16 + lm) * 32 + q8];
#pragma unroll
    for (int j = 0; j < 2; j++) {
      b1[j] = *(const bf16x8*)&B1s[cur][(wc + j * 16 + lm) * 32 + q8];
      b3[j] = *(const bf16x8*)&B3s[cur][(wc + j * 16 + lm) * 32 + q8];
    }
#pragma unroll
    for (int i = 0; i < 4; i++)
#pragma unroll
      for (int j = 0; j < 2; j++) {
        acc1[i][j] = __builtin_amdgcn_mfma_f32_16x16x32_bf16(a[i], b1[j], acc1[i][j], 0, 0, 0);
        acc3[i][j] = __builtin_amdgcn_mfma_f32_16x16x32_bf16(a[i], b3[j], acc3[i][j], 0, 0, 0);
      }
  }

#pragma unroll
  for (int i = 0; i < 4; i++) {
#pragma unroll
    for (int r = 0; r < 4; r++) {
      int ml = wr + i * 16 + (lane >> 4) * 4 + r;
      int mg = m0 + ml;
      if (mg < count) {
        unsigned short* hp = h + (size_t)(sbase + mg) * FDIM + n0 + wc + lm;
#pragma unroll
        for (int j = 0; j < 2; j++) {
          float v1 = acc1[i][j][r];
          float v3 = acc3[i][j][r];
          float hv = (v1 / (1.0f + __expf(-v1))) * v3;
          hp[j * 16] = f2bf(hv);
        }
      }
    }
  }
}

// ---------------- GEMM2: y[slot] = h[slot] @ w2 ------------------------------
// Block tile 128(M) x 64(N), wave tile 64x32. acc = 8 f32x4 = 32 AGPR.
// launch_bounds(256,4) -> 4 waves/SIMD.
__global__ __launch_bounds__(256, 4) void gemm2_kernel(
    const unsigned short* __restrict__ h,    // [T*2][F] bf16
    const unsigned short* __restrict__ w2t,  // [E][D][F] bf16
    const int* __restrict__ hdr,
    float* __restrict__ y)                   // [T*2][D] fp32 (slot space)
{
  const int e = blockIdx.z;
  const int count = hdr[e];
  const int m0 = blockIdx.y * 128;
  if (m0 >= count) return;
  const int n0 = blockIdx.x * 64;
  const int sbase = hdr[16 + e];

  __shared__ unsigned short Ahs[2][4096];  // 128 x 32
  __shared__ unsigned short Bs[2][2048];   // 64 x 32

  const int tid = threadIdx.x;
  const int kcol = (tid & 3) * 8;
  const int r0 = tid >> 2;
  int mr0 = m0 + r0;      if (mr0 > count - 1) mr0 = count - 1;
  int mr1 = m0 + r0 + 64; if (mr1 > count - 1) mr1 = count - 1;
  const unsigned short* pA0 = h + (size_t)(sbase + mr0) * FDIM + kcol;
  const unsigned short* pA1 = h + (size_t)(sbase + mr1) * FDIM + kcol;
  const unsigned short* pB = w2t + ((size_t)e * DDIM + n0 + r0) * FDIM + kcol;
  const int l0 = tid * 8;

  const int wv = tid >> 6;
  const int wr = (wv >> 1) * 64;
  const int wc = (wv & 1) * 32;
  const int lane = tid & 63;
  const int q8 = (lane >> 4) * 8;
  const int lm = lane & 15;

  f32x4 acc[4][2];
#pragma unroll
  for (int i = 0; i < 4; i++)
#pragma unroll
    for (int j = 0; j < 2; j++) acc[i][j] = f32x4{0.f, 0.f, 0.f, 0.f};

  async_cp16(pA0, &Ahs[0][l0]);
  async_cp16(pA1, &Ahs[0][l0 + 2048]);
  async_cp16(pB, &Bs[0][l0]);

  for (int kt = 0; kt < FDIM; kt += 32) {
    const int cur = (kt >> 5) & 1;
    __syncthreads();
    if (kt + 32 < FDIM) {
      const int nxt = cur ^ 1;
      async_cp16(pA0 + kt + 32, &Ahs[nxt][l0]);
      async_cp16(pA1 + kt + 32, &Ahs[nxt][l0 + 2048]);
      async_cp16(pB + kt + 32, &Bs[nxt][l0]);
    }

    bf16x8 a[4], b[2];
#pragma unroll
    for (int i = 0; i < 4; i++)
      a[i] = *(const bf16x8*)&Ahs[cur][(wr + i * 16 + lm) * 32 + q8];
#pragma unroll
    for (int j = 0; j < 2; j++)
      b[j] = *(const bf16x8*)&Bs[cur][(wc + j * 16 + lm) * 32 + q8];
#pragma unroll
    for (int i = 0; i < 4; i++)
#pragma unroll
      for (int j = 0; j < 2; j++)
        acc[i][j] = __builtin_amdgcn_mfma_f32_16x16x32_bf16(a[i], b[j], acc[i][j], 0, 0, 0);
  }

#pragma unroll
  for (int i = 0; i < 4; i++) {
#pragma unroll
    for (int r = 0; r < 4; r++) {
      int ml = wr + i * 16 + (lane >> 4) * 4 + r;
      int mg = m0 + ml;
      if (mg < count) {
        float* yp = y + (size_t)(sbase + mg) * DDIM + n0 + wc + lm;
#pragma unroll
        for (int j = 0; j < 2; j++) yp[j * 16] = acc[i][j][r];
      }
    }
  }
}

// ---------------- combine: out[t] = p0*y[s0] + p1*y[s1] ----------------
__global__ __launch_bounds__(256) void combine_kernel(const float* __restrict__ y,
                                                      const int* __restrict__ slot_of,
                                                      const float* __restrict__ prb,
                                                      float* __restrict__ out) {
  int t = blockIdx.x;
  int s0 = slot_of[t * 2], s1 = slot_of[t * 2 + 1];
  float p0 = prb[t * 2], p1 = prb[t * 2 + 1];
  float4 a = ((const float4*)(y + (size_t)s0 * DDIM))[threadIdx.x];
  float4 b = ((const float4*)(y + (size_t)s1 * DDIM))[threadIdx.x];
  float4 o;
  o.x = p0 * a.x + p1 * b.x;
  o.y = p0 * a.y + p1 * b.y;
  o.z = p0 * a.z + p1 * b.z;
  o.w = p0 * a.w + p1 * b.w;
  ((float4*)(out + (size_t)t * DDIM))[threadIdx.x] = o;
}

extern "C" void kernel_launch(void* const* d_in, const int* in_sizes, int n_in,
                              void* d_out, int out_size, void* d_ws, size_t ws_size,
                              hipStream_t stream) {
  const float* x  = (const float*)d_in[0];
  const float* wg = (const float*)d_in[1];
  const float* w1 = (const float*)d_in[2];
  const float* w3 = (const float*)d_in[3];
  const float* w2 = (const float*)d_in[4];
  float* out = (float*)d_out;
  char* ws = (char*)d_ws;

  size_t off = 0;
  int* hdr = (int*)(ws + off); off += 256;
  int* sel = (int*)(ws + off); off += (size_t)T_TOK * 2 * 4;
  float* prb = (float*)(ws + off); off += (size_t)T_TOK * 2 * 4;
  int* rows = (int*)(ws + off); off += (size_t)T_TOK * 2 * 4;
  int* slot_of = (int*)(ws + off); off += (size_t)T_TOK * 2 * 4;
  unsigned short* xb  = (unsigned short*)(ws + off); off += (size_t)T_TOK * DDIM * 2;
  unsigned short* w1t = (unsigned short*)(ws + off); off += (size_t)EEXP * DDIM * FDIM * 2;
  unsigned short* w3t = (unsigned short*)(ws + off); off += (size_t)EEXP * DDIM * FDIM * 2;
  unsigned short* w2t = (unsigned short*)(ws + off); off += (size_t)EEXP * DDIM * FDIM * 2;
  unsigned short* h   = (unsigned short*)(ws + off); off += (size_t)T_TOK * 2 * FDIM * 2;
  // y overlays w1t+w3t (64 MB, dead after gemm1): [T*2][D] fp32
  float* y = (float*)w1t;

  hipMemsetAsync(hdr, 0, 256, stream);

  castx_kernel<<<T_TOK * DDIM / 4 / 256, 256, 0, stream>>>(x, xb, T_TOK * DDIM / 4);
  transpose_cast_kernel<<<dim3(FDIM / 64, DDIM / 64, EEXP), dim3(64, 4), 0, stream>>>(w1, w1t, DDIM, FDIM);
  transpose_cast_kernel<<<dim3(FDIM / 64, DDIM / 64, EEXP), dim3(64, 4), 0, stream>>>(w3, w3t, DDIM, FDIM);
  transpose_cast_kernel<<<dim3(DDIM / 64, FDIM / 64, EEXP), dim3(64, 4), 0, stream>>>(w2, w2t, FDIM, DDIM);
  gate_kernel<<<T_TOK / 4, 256, 0, stream>>>(x, wg, sel, prb, hdr);
  scan_kernel<<<1, 64, 0, stream>>>(hdr);
  build_kernel<<<(T_TOK * 2 + 255) / 256, 256, 0, stream>>>(sel, prb, hdr, rows, slot_of);
  gemm1_kernel<<<dim3(FDIM / 64, T_TOK / 128, EEXP), 256, 0, stream>>>(xb, w1t, w3t, rows, hdr, h);
  gemm2_kernel<<<dim3(DDIM / 64, T_TOK / 128, EEXP), 256, 0, stream>>>(h, w2t, hdr, y);
  combine_kernel<<<T_TOK, 256, 0, stream>>>(y, slot_of, prb, out);
}

// Round 4
// 847.845 us; speedup vs baseline: 1.2025x; 1.0122x over previous
//
#include <hip/hip_runtime.h>
#include <stdint.h>

#define T_TOK 8192
#define DDIM 1024
#define EEXP 8
#define FDIM 2048

typedef float f32x4 __attribute__((ext_vector_type(4)));
typedef __bf16 bf16x8 __attribute__((ext_vector_type(8)));

__device__ __forceinline__ unsigned short f2bf(float f) {
  union { float f; unsigned int u; } v; v.f = f;
  unsigned int r = (v.u + 0x7fffu + ((v.u >> 16) & 1u)) >> 16;
  return (unsigned short)r;
}

__device__ __forceinline__ void async_cp16(const void* g, void* l) {
  __builtin_amdgcn_global_load_lds(
      (const __attribute__((address_space(1))) unsigned int*)g,
      (__attribute__((address_space(3))) unsigned int*)l, 16, 0, 0);
}

// ---------------- cast x fp32 -> bf16 ----------------
__global__ __launch_bounds__(256) void castx_kernel(const float* __restrict__ in,
                                                    unsigned short* __restrict__ out,
                                                    int n4) {
  int i = blockIdx.x * 256 + threadIdx.x;
  if (i >= n4) return;
  float4 v = ((const float4*)in)[i];
  ushort4 o;
  o.x = f2bf(v.x); o.y = f2bf(v.y); o.z = f2bf(v.z); o.w = f2bf(v.w);
  ((ushort4*)out)[i] = o;
}

// ---------------- transpose-cast weights ----------------
// in [e][R][C] fp32 -> out [e][C][R] bf16; dual-source variant for w1/w3.
__global__ __launch_bounds__(256) void transpose_cast2_kernel(const float* __restrict__ inA,
                                                              const float* __restrict__ inB,
                                                              unsigned short* __restrict__ outA,
                                                              unsigned short* __restrict__ outB,
                                                              int R, int C) {
  __shared__ float tile[64][65];
  const int z = blockIdx.z;
  const float* in = (z < EEXP) ? inA : inB;
  unsigned short* out = (z < EEXP) ? outA : outB;
  const size_t ebase = (size_t)(z & 7) * R * C;
  int c0 = blockIdx.x * 64;
  int r0 = blockIdx.y * 64;
  int tx = threadIdx.x;
  int ty = threadIdx.y;
#pragma unroll
  for (int i = 0; i < 64; i += 4)
    tile[ty + i][tx] = in[ebase + (size_t)(r0 + ty + i) * C + c0 + tx];
  __syncthreads();
#pragma unroll
  for (int i = 0; i < 64; i += 4)
    out[ebase + (size_t)(c0 + ty + i) * R + r0 + tx] = f2bf(tile[tx][ty + i]);
}

// ---------------- gating: wave per token ----------------
// hdr layout (ints): [0..7]=cnt, [8..15]=fill, [16..24]=offs
__global__ __launch_bounds__(256) void gate_kernel(const float* __restrict__ x,
                                                   const float* __restrict__ wg,
                                                   int* __restrict__ sel,
                                                   float* __restrict__ prb,
                                                   int* __restrict__ hdr) {
  __shared__ float wgs[8 * 1024];  // transposed [e][d]
  int tid = threadIdx.x;
  for (int i = tid; i < 8192; i += 256) {
    int d = i >> 3, e = i & 7;
    wgs[e * 1024 + d] = wg[i];
  }
  __syncthreads();
  int lane = tid & 63;
  int t = blockIdx.x * 4 + (tid >> 6);
  const float* xr = x + (size_t)t * 1024;
  float acc[8] = {0.f, 0.f, 0.f, 0.f, 0.f, 0.f, 0.f, 0.f};
  for (int d = lane; d < 1024; d += 64) {
    float xv = xr[d];
#pragma unroll
    for (int e = 0; e < 8; e++) acc[e] += xv * wgs[e * 1024 + d];
  }
#pragma unroll
  for (int e = 0; e < 8; e++) {
    acc[e] += __shfl_xor(acc[e], 32);
    acc[e] += __shfl_xor(acc[e], 16);
    acc[e] += __shfl_xor(acc[e], 8);
    acc[e] += __shfl_xor(acc[e], 4);
    acc[e] += __shfl_xor(acc[e], 2);
    acc[e] += __shfl_xor(acc[e], 1);
  }
  if (lane == 0) {
    int i0 = 0; float v0 = acc[0];
#pragma unroll
    for (int e = 1; e < 8; e++) if (acc[e] > v0) { v0 = acc[e]; i0 = e; }
    int i1 = -1; float v1 = -1e30f;
#pragma unroll
    for (int e = 0; e < 8; e++) if (e != i0 && acc[e] > v1) { v1 = acc[e]; i1 = e; }
    float ex = __expf(v1 - v0);
    float inv = 1.0f / (1.0f + ex);
    sel[t * 2] = i0; sel[t * 2 + 1] = i1;
    prb[t * 2] = inv; prb[t * 2 + 1] = ex * inv;
    atomicAdd(&hdr[i0], 1);
    atomicAdd(&hdr[i1], 1);
  }
}

__global__ void scan_kernel(int* hdr) {
  if (threadIdx.x == 0 && blockIdx.x == 0) {
    int s = 0;
    for (int e = 0; e < 8; e++) { hdr[16 + e] = s; s += hdr[e]; }
    hdr[24] = s;
  }
}

__global__ __launch_bounds__(256) void build_kernel(const int* __restrict__ sel,
                                                    const float* __restrict__ prb,
                                                    int* __restrict__ hdr,
                                                    int* __restrict__ rows,
                                                    int* __restrict__ slot_of) {
  int i = blockIdx.x * 256 + threadIdx.x;
  if (i >= T_TOK * 2) return;
  int e = sel[i];
  int pos = hdr[16 + e] + atomicAdd(&hdr[8 + e], 1);
  rows[pos] = i >> 1;
  slot_of[i] = pos;
}

// LDS bank swizzle: physical k-group = logical ^ ((row>>1)&3).
// Load side: thread tid stages phys slot (row=tid>>2, p=tid&3) from logical
// k-offset ((tid&3)^((tid>>3)&3))*8. Read side: q8s below. 16 lanes of a frag
// then span 8 distinct 4-bank groups at 2-way aliasing (free) instead of 8-way.

// ---------------- GEMM1: h = silu(x@w1)*(x@w3) ------------------------------
// Block 128(M) x 64(N), 4 waves 2x2, wave 64x32 dual-B. acc 64 AGPR, 3 w/SIMD.
__global__ __launch_bounds__(256, 3) void gemm1_kernel(
    const unsigned short* __restrict__ xb,   // [T][D] bf16
    const unsigned short* __restrict__ w1t,  // [E][F][D] bf16
    const unsigned short* __restrict__ w3t,  // [E][F][D] bf16
    const int* __restrict__ rows,            // slot -> token
    const int* __restrict__ hdr,
    unsigned short* __restrict__ h)          // [T*2][F] bf16 (slot space)
{
  const int e = blockIdx.z;
  const int count = hdr[e];
  const int m0 = blockIdx.y * 128;
  if (m0 >= count) return;
  const int n0 = blockIdx.x * 64;
  const int sbase = hdr[16 + e];

  __shared__ unsigned short As[2][4096];   // 128 x 32
  __shared__ unsigned short B1s[2][2048];  // 64 x 32
  __shared__ unsigned short B3s[2][2048];  // 64 x 32

  const int tid = threadIdx.x;
  const int kcol = (((tid & 3) ^ ((tid >> 3) & 3))) * 8;  // swizzled fetch col
  const int r0 = tid >> 2;                 // 0..63
  int mr0 = m0 + r0;      if (mr0 > count - 1) mr0 = count - 1;
  int mr1 = m0 + r0 + 64; if (mr1 > count - 1) mr1 = count - 1;
  const int tok0 = rows[sbase + mr0];
  const int tok1 = rows[sbase + mr1];
  const unsigned short* pA0 = xb + (size_t)tok0 * DDIM + kcol;
  const unsigned short* pA1 = xb + (size_t)tok1 * DDIM + kcol;
  const unsigned short* pB1 = w1t + ((size_t)e * FDIM + n0 + r0) * DDIM + kcol;
  const unsigned short* pB3 = w3t + ((size_t)e * FDIM + n0 + r0) * DDIM + kcol;
  const int l0 = tid * 8;

  const int wv = tid >> 6;
  const int wr = (wv >> 1) * 64;           // 0 / 64
  const int wc = (wv & 1) * 32;            // 0 / 32
  const int lane = tid & 63;
  const int q8s = (((lane >> 4) ^ ((lane >> 1) & 3))) * 8;  // swizzled read col
  const int lm = lane & 15;

  f32x4 acc1[4][2], acc3[4][2];
#pragma unroll
  for (int i = 0; i < 4; i++)
#pragma unroll
    for (int j = 0; j < 2; j++) {
      acc1[i][j] = f32x4{0.f, 0.f, 0.f, 0.f};
      acc3[i][j] = f32x4{0.f, 0.f, 0.f, 0.f};
    }

  async_cp16(pA0, &As[0][l0]);
  async_cp16(pA1, &As[0][l0 + 2048]);
  async_cp16(pB1, &B1s[0][l0]);
  async_cp16(pB3, &B3s[0][l0]);

  for (int kt = 0; kt < DDIM; kt += 32) {
    const int cur = (kt >> 5) & 1;
    __syncthreads();
    if (kt + 32 < DDIM) {
      const int nxt = cur ^ 1;
      async_cp16(pA0 + kt + 32, &As[nxt][l0]);
      async_cp16(pA1 + kt + 32, &As[nxt][l0 + 2048]);
      async_cp16(pB1 + kt + 32, &B1s[nxt][l0]);
      async_cp16(pB3 + kt + 32, &B3s[nxt][l0]);
    }

    bf16x8 a[4], b1[2], b3[2];
#pragma unroll
    for (int i = 0; i < 4; i++)
      a[i] = *(const bf16x8*)&As[cur][(wr + i * 16 + lm) * 32 + q8s];
#pragma unroll
    for (int j = 0; j < 2; j++) {
      b1[j] = *(const bf16x8*)&B1s[cur][(wc + j * 16 + lm) * 32 + q8s];
      b3[j] = *(const bf16x8*)&B3s[cur][(wc + j * 16 + lm) * 32 + q8s];
    }
#pragma unroll
    for (int i = 0; i < 4; i++)
#pragma unroll
      for (int j = 0; j < 2; j++) {
        acc1[i][j] = __builtin_amdgcn_mfma_f32_16x16x32_bf16(a[i], b1[j], acc1[i][j], 0, 0, 0);
        acc3[i][j] = __builtin_amdgcn_mfma_f32_16x16x32_bf16(a[i], b3[j], acc3[i][j], 0, 0, 0);
      }
  }

#pragma unroll
  for (int i = 0; i < 4; i++) {
#pragma unroll
    for (int r = 0; r < 4; r++) {
      int ml = wr + i * 16 + (lane >> 4) * 4 + r;
      int mg = m0 + ml;
      if (mg < count) {
        unsigned short* hp = h + (size_t)(sbase + mg) * FDIM + n0 + wc + lm;
#pragma unroll
        for (int j = 0; j < 2; j++) {
          float v1 = acc1[i][j][r];
          float v3 = acc3[i][j][r];
          float hv = (v1 / (1.0f + __expf(-v1))) * v3;
          hp[j * 16] = f2bf(hv);
        }
      }
    }
  }
}

// ---------------- GEMM2: y[slot] = h[slot] @ w2 ------------------------------
// Block 128(M) x 128(N), 4 waves 2x2, wave 64x64. acc 64 AGPR, 3 w/SIMD.
__global__ __launch_bounds__(256, 3) void gemm2_kernel(
    const unsigned short* __restrict__ h,    // [T*2][F] bf16
    const unsigned short* __restrict__ w2t,  // [E][D][F] bf16
    const int* __restrict__ hdr,
    float* __restrict__ y)                   // [T*2][D] fp32 (slot space)
{
  const int e = blockIdx.z;
  const int count = hdr[e];
  const int m0 = blockIdx.y * 128;
  if (m0 >= count) return;
  const int n0 = blockIdx.x * 128;
  const int sbase = hdr[16 + e];

  __shared__ unsigned short Ahs[2][4096];  // 128 x 32
  __shared__ unsigned short Bs[2][4096];   // 128 x 32

  const int tid = threadIdx.x;
  const int kcol = (((tid & 3) ^ ((tid >> 3) & 3))) * 8;
  const int r0 = tid >> 2;
  int mr0 = m0 + r0;      if (mr0 > count - 1) mr0 = count - 1;
  int mr1 = m0 + r0 + 64; if (mr1 > count - 1) mr1 = count - 1;
  const unsigned short* pA0 = h + (size_t)(sbase + mr0) * FDIM + kcol;
  const unsigned short* pA1 = h + (size_t)(sbase + mr1) * FDIM + kcol;
  const unsigned short* pB0 = w2t + ((size_t)e * DDIM + n0 + r0) * FDIM + kcol;
  const unsigned short* pB1 = w2t + ((size_t)e * DDIM + n0 + r0 + 64) * FDIM + kcol;
  const int l0 = tid * 8;

  const int wv = tid >> 6;
  const int wr = (wv >> 1) * 64;
  const int wc = (wv & 1) * 64;
  const int lane = tid & 63;
  const int q8s = (((lane >> 4) ^ ((lane >> 1) & 3))) * 8;
  const int lm = lane & 15;

  f32x4 acc[4][4];
#pragma unroll
  for (int i = 0; i < 4; i++)
#pragma unroll
    for (int j = 0; j < 4; j++) acc[i][j] = f32x4{0.f, 0.f, 0.f, 0.f};

  async_cp16(pA0, &Ahs[0][l0]);
  async_cp16(pA1, &Ahs[0][l0 + 2048]);
  async_cp16(pB0, &Bs[0][l0]);
  async_cp16(pB1, &Bs[0][l0 + 2048]);

  for (int kt = 0; kt < FDIM; kt += 32) {
    const int cur = (kt >> 5) & 1;
    __syncthreads();
    if (kt + 32 < FDIM) {
      const int nxt = cur ^ 1;
      async_cp16(pA0 + kt + 32, &Ahs[nxt][l0]);
      async_cp16(pA1 + kt + 32, &Ahs[nxt][l0 + 2048]);
      async_cp16(pB0 + kt + 32, &Bs[nxt][l0]);
      async_cp16(pB1 + kt + 32, &Bs[nxt][l0 + 2048]);
    }

    bf16x8 a[4], b[4];
#pragma unroll
    for (int i = 0; i < 4; i++)
      a[i] = *(const bf16x8*)&Ahs[cur][(wr + i * 16 + lm) * 32 + q8s];
#pragma unroll
    for (int j = 0; j < 4; j++)
      b[j] = *(const bf16x8*)&Bs[cur][(wc + j * 16 + lm) * 32 + q8s];
#pragma unroll
    for (int i = 0; i < 4; i++)
#pragma unroll
      for (int j = 0; j < 4; j++)
        acc[i][j] = __builtin_amdgcn_mfma_f32_16x16x32_bf16(a[i], b[j], acc[i][j], 0, 0, 0);
  }

#pragma unroll
  for (int i = 0; i < 4; i++) {
#pragma unroll
    for (int r = 0; r < 4; r++) {
      int ml = wr + i * 16 + (lane >> 4) * 4 + r;
      int mg = m0 + ml;
      if (mg < count) {
        float* yp = y + (size_t)(sbase + mg) * DDIM + n0 + wc + lm;
#pragma unroll
        for (int j = 0; j < 4; j++) yp[j * 16] = acc[i][j][r];
      }
    }
  }
}

// ---------------- combine: out[t] = p0*y[s0] + p1*y[s1] ----------------
__global__ __launch_bounds__(256) void combine_kernel(const float* __restrict__ y,
                                                      const int* __restrict__ slot_of,
                                                      const float* __restrict__ prb,
                                                      float* __restrict__ out) {
  int t = blockIdx.x;
  int s0 = slot_of[t * 2], s1 = slot_of[t * 2 + 1];
  float p0 = prb[t * 2], p1 = prb[t * 2 + 1];
  float4 a = ((const float4*)(y + (size_t)s0 * DDIM))[threadIdx.x];
  float4 b = ((const float4*)(y + (size_t)s1 * DDIM))[threadIdx.x];
  float4 o;
  o.x = p0 * a.x + p1 * b.x;
  o.y = p0 * a.y + p1 * b.y;
  o.z = p0 * a.z + p1 * b.z;
  o.w = p0 * a.w + p1 * b.w;
  ((float4*)(out + (size_t)t * DDIM))[threadIdx.x] = o;
}

extern "C" void kernel_launch(void* const* d_in, const int* in_sizes, int n_in,
                              void* d_out, int out_size, void* d_ws, size_t ws_size,
                              hipStream_t stream) {
  const float* x  = (const float*)d_in[0];
  const float* wg = (const float*)d_in[1];
  const float* w1 = (const float*)d_in[2];
  const float* w3 = (const float*)d_in[3];
  const float* w2 = (const float*)d_in[4];
  float* out = (float*)d_out;
  char* ws = (char*)d_ws;

  size_t off = 0;
  int* hdr = (int*)(ws + off); off += 256;
  int* sel = (int*)(ws + off); off += (size_t)T_TOK * 2 * 4;
  float* prb = (float*)(ws + off); off += (size_t)T_TOK * 2 * 4;
  int* rows = (int*)(ws + off); off += (size_t)T_TOK * 2 * 4;
  int* slot_of = (int*)(ws + off); off += (size_t)T_TOK * 2 * 4;
  unsigned short* xb  = (unsigned short*)(ws + off); off += (size_t)T_TOK * DDIM * 2;
  unsigned short* w1t = (unsigned short*)(ws + off); off += (size_t)EEXP * DDIM * FDIM * 2;
  unsigned short* w3t = (unsigned short*)(ws + off); off += (size_t)EEXP * DDIM * FDIM * 2;
  unsigned short* w2t = (unsigned short*)(ws + off); off += (size_t)EEXP * DDIM * FDIM * 2;
  unsigned short* h   = (unsigned short*)(ws + off); off += (size_t)T_TOK * 2 * FDIM * 2;
  // y overlays w1t+w3t (64 MB, dead after gemm1): [T*2][D] fp32
  float* y = (float*)w1t;

  hipMemsetAsync(hdr, 0, 256, stream);

  castx_kernel<<<T_TOK * DDIM / 4 / 256, 256, 0, stream>>>(x, xb, T_TOK * DDIM / 4);
  transpose_cast2_kernel<<<dim3(FDIM / 64, DDIM / 64, EEXP * 2), dim3(64, 4), 0, stream>>>(
      w1, w3, w1t, w3t, DDIM, FDIM);
  transpose_cast2_kernel<<<dim3(DDIM / 64, FDIM / 64, EEXP), dim3(64, 4), 0, stream>>>(
      w2, w2, w2t, w2t, FDIM, DDIM);
  gate_kernel<<<T_TOK / 4, 256, 0, stream>>>(x, wg, sel, prb, hdr);
  scan_kernel<<<1, 64, 0, stream>>>(hdr);
  build_kernel<<<(T_TOK * 2 + 255) / 256, 256, 0, stream>>>(sel, prb, hdr, rows, slot_of);
  gemm1_kernel<<<dim3(FDIM / 64, T_TOK / 128, EEXP), 256, 0, stream>>>(xb, w1t, w3t, rows, hdr, h);
  gemm2_kernel<<<dim3(DDIM / 128, T_TOK / 128, EEXP), 256, 0, stream>>>(h, w2t, hdr, y);
  combine_kernel<<<T_TOK, 256, 0, stream>>>(y, slot_of, prb, out);
}